// Round 1
// baseline (3103.973 us; speedup 1.0000x reference)
//
#include <hip/hip_runtime.h>
#include <math.h>

#define SEQ   2048
#define BATCH 128
#define HID   256
#define KHALF 128   // each thread owns half of the K reduction

// One block per batch row. 512 threads = (j in [0,256)) x (half in {0,1}).
// Thread (j, half) holds W_eff[j][half*128 .. half*128+127] in VGPRs.
// h for this batch row lives in LDS; per step each thread does 128 FMAs
// against wave-uniform float4 broadcasts of h, halves are combined via LDS,
// tanh + noise applied, h written back to LDS + global out, and the y-dot
// (out @ W[0]) is reduced in-step via 64-lane shuffles.
__global__ __launch_bounds__(512, 2) void Net_46368466927789_kernel(
    const float* __restrict__ x,      // (SEQ, BATCH)
    const float* __restrict__ h0,     // (BATCH, HID)
    const float* __restrict__ noise,  // (SEQ, BATCH, HID)
    const float* __restrict__ W_ih,   // (HID, 1)
    const float* __restrict__ W_hh,   // (HID, HID)
    const float* __restrict__ W_hhb,  // (HID, HID)
    const float* __restrict__ b_h,    // (HID)
    const float* __restrict__ W,      // (OUT, HID)
    const float* __restrict__ bvec,   // (OUT)
    const int*   __restrict__ ctx,    // scalar
    float* __restrict__ y_out,        // (BATCH, SEQ)
    float* __restrict__ h_out)        // (BATCH, SEQ, HID)
{
    const int b    = blockIdx.x;
    const int tid  = threadIdx.x;
    const int j    = tid & (HID - 1);
    const int half = tid >> 8;        // 0 or 1
    const int wave = tid >> 6;        // 0..7
    const int lane = tid & 63;

    // context arrives as a 1-element array; defend against int32 vs float32 encoding
    int iv = *ctx;
    float c = (iv > 1000000 || iv < -1000000) ? __int_as_float(iv) : (float)iv;

    __shared__ float h_lds[HID];
    __shared__ float part[HID];
    __shared__ float yred[8];

    // Load this thread's W_eff slice into registers (one-time, L2/L3-cached).
    float wreg[KHALF];
    {
        const float* wr  = &W_hh [j * HID + half * KHALF];
        const float* wrb = &W_hhb[j * HID + half * KHALF];
        #pragma unroll
        for (int k = 0; k < KHALF; ++k)
            wreg[k] = wr[k] + c * wrb[k];
    }

    const float win   = W_ih[j];   // W_ih[j][0]
    const float bh    = b_h[j];
    const float w0    = W[j];      // W[0][j]
    const float bias0 = bvec[0];

    if (tid < HID) h_lds[tid] = h0[b * HID + tid];
    __syncthreads();

    for (int t = 0; t < SEQ; ++t) {
        // ---- dot over this thread's K half (LDS float4 broadcasts) ----
        float a0 = 0.f, a1 = 0.f, a2 = 0.f, a3 = 0.f;
        const float4* hp = (const float4*)&h_lds[half * KHALF];
        #pragma unroll
        for (int k4 = 0; k4 < KHALF / 4; ++k4) {
            float4 h4 = hp[k4];
            a0 += h4.x * wreg[4 * k4 + 0];
            a1 += h4.y * wreg[4 * k4 + 1];
            a2 += h4.z * wreg[4 * k4 + 2];
            a3 += h4.w * wreg[4 * k4 + 3];
        }
        float acc = (a0 + a1) + (a2 + a3);

        __syncthreads();                    // all reads of old h done
        if (half) part[j] = acc;
        __syncthreads();                    // partials visible; h_lds writable

        float p = 0.f;
        if (!half) {
            float z  = acc + part[j] + x[t * BATCH + b] * win + bh;
            // tanh(z) = 1 - 2/(exp(2z)+1); saturates correctly at +/-inf
            float e  = __expf(2.f * z);
            float th = 1.f - 2.f / (e + 1.f);
            float hn = th + noise[((size_t)t * BATCH + b) * HID + j];
            h_lds[j] = hn;
            h_out[((size_t)b * SEQ + t) * HID + j] = hn;
            p = hn * w0;
        }
        // 64-lane butterfly reduce of p (waves 0..3 carry real data)
        #pragma unroll
        for (int s = 32; s; s >>= 1) p += __shfl_xor(p, s, 64);
        if (!half && lane == 0) yred[wave] = p;

        __syncthreads();                    // new h + yred visible
        if (tid == 0) {
            float z = yred[0] + yred[1] + yred[2] + yred[3] + bias0;
            y_out[(size_t)b * SEQ + t] = 1.f / (1.f + __expf(-z));
        }
    }
}

extern "C" void kernel_launch(void* const* d_in, const int* in_sizes, int n_in,
                              void* d_out, int out_size, void* d_ws, size_t ws_size,
                              hipStream_t stream) {
    const float* x     = (const float*)d_in[0];
    const float* h0    = (const float*)d_in[1];
    const float* noise = (const float*)d_in[2];
    const float* W_ih  = (const float*)d_in[3];
    const float* W_hh  = (const float*)d_in[4];
    const float* W_hhb = (const float*)d_in[5];
    const float* b_h   = (const float*)d_in[6];
    const float* W     = (const float*)d_in[7];
    const float* bvec  = (const float*)d_in[8];
    const int*   ctx   = (const int*)d_in[9];

    float* y_out = (float*)d_out;                         // (BATCH, SEQ)
    float* h_out = (float*)d_out + (size_t)BATCH * SEQ;   // (BATCH, SEQ, HID)

    Net_46368466927789_kernel<<<dim3(BATCH), dim3(512), 0, stream>>>(
        x, h0, noise, W_ih, W_hh, W_hhb, b_h, W, bvec, ctx, y_out, h_out);
}

// Round 2
// 3004.821 us; speedup vs baseline: 1.0330x; 1.0330x over previous
//
#include <hip/hip_runtime.h>
#include <math.h>

#define SEQ   2048
#define BATCH 128
#define HID   256
#define KH    128   // K-half per thread

// One block per batch row; 512 threads = pairs (j = tid>>1, half = tid&1).
// Thread (j,half) holds W_eff[j][half*128 ..+127] in 128 VGPRs.
// Per step: 128 FMAs vs LDS float4 broadcasts of h (pair = 2-way, conflict-free),
// halves combined with ONE __shfl_xor (same wave), tanh + prefetched noise,
// double-buffered h in LDS -> single barrier per step.
__global__ __launch_bounds__(512, 2) void rnn_kernel(
    const float* __restrict__ x,      // (SEQ, BATCH)
    const float* __restrict__ h0,     // (BATCH, HID)
    const float* __restrict__ noise,  // (SEQ, BATCH, HID)
    const float* __restrict__ W_ih,   // (HID, 1)
    const float* __restrict__ W_hh,   // (HID, HID)
    const float* __restrict__ W_hhb,  // (HID, HID)
    const float* __restrict__ b_h,    // (HID)
    const int*   __restrict__ ctx,    // scalar
    float* __restrict__ h_out)        // (BATCH, SEQ, HID)
{
    const int b    = blockIdx.x;
    const int tid  = threadIdx.x;
    const int j    = tid >> 1;
    const int half = tid & 1;
    const bool even = (half == 0);

    __shared__ float hbuf[2][HID];

    int iv = *ctx;
    float c = (iv > 1000000 || iv < -1000000) ? __int_as_float(iv) : (float)iv;

    // One-time: W_eff slice into registers (L2/L3-cached reads).
    float wreg[KH];
    {
        const float* wr  = &W_hh [j * HID + half * KH];
        const float* wrb = &W_hhb[j * HID + half * KH];
        #pragma unroll
        for (int k = 0; k < KH; ++k)
            wreg[k] = wr[k] + c * wrb[k];
    }

    const float win = W_ih[j];
    const float bh  = b_h[j];

    if (tid < HID) hbuf[0][tid] = h0[b * HID + tid];

    // Prefetch t=0 inputs (hidden behind the weight-load latency).
    float x_next = x[b];
    float n_next = even ? noise[(size_t)b * HID + j] : 0.f;

    float* hout_b = h_out + (size_t)b * SEQ * HID;

    __syncthreads();

    for (int t = 0; t < SEQ; ++t) {
        const int cur = t & 1, nxt = cur ^ 1;
        const float x_t = x_next;
        const float n_t = n_next;

        // Prefetch step t+1 (off the dependent chain; waits resolve during dot).
        const int tn = (t + 1 < SEQ) ? t + 1 : t;
        x_next = x[tn * BATCH + b];
        if (even) n_next = noise[((size_t)tn * BATCH + b) * HID + j];

        // ---- 128-FMA dot vs LDS broadcasts ----
        float a0=0.f,a1=0.f,a2=0.f,a3=0.f,a4=0.f,a5=0.f,a6=0.f,a7=0.f;
        const float4* hp = (const float4*)&hbuf[cur][half * KH];
        #pragma unroll
        for (int k8 = 0; k8 < KH / 8; ++k8) {
            float4 u = hp[2 * k8];
            float4 v = hp[2 * k8 + 1];
            a0 += u.x * wreg[8*k8+0];  a1 += u.y * wreg[8*k8+1];
            a2 += u.z * wreg[8*k8+2];  a3 += u.w * wreg[8*k8+3];
            a4 += v.x * wreg[8*k8+4];  a5 += v.y * wreg[8*k8+5];
            a6 += v.z * wreg[8*k8+6];  a7 += v.w * wreg[8*k8+7];
        }
        float acc = ((a0+a1)+(a2+a3)) + ((a4+a5)+(a6+a7));
        acc += __shfl_xor(acc, 1, 64);   // combine the two halves (same wave)

        if (even) {
            float z  = acc + x_t * win + bh;
            float e  = __expf(2.f * z);          // tanh(z) = 1 - 2/(e^{2z}+1)
            float hn = 1.f - 2.f / (e + 1.f) + n_t;
            hbuf[nxt][j] = hn;
            hout_b[(size_t)t * HID + j] = hn;    // store: non-blocking
        }
        __syncthreads();   // new h visible; old buffer free for overwrite next step
    }
}

// y[b][t] = sigmoid(dot(h_out[b][t][:], W[0][:]) + bias0). One wave per (b,t).
__global__ __launch_bounds__(256) void yproj_kernel(
    const float* __restrict__ h_out,  // (BATCH, SEQ, HID)
    const float* __restrict__ W,      // (OUT, HID) -> row 0
    const float* __restrict__ bvec,   // (OUT)
    float* __restrict__ y_out)        // (BATCH, SEQ)
{
    const int gw   = blockIdx.x * 4 + (threadIdx.x >> 6);  // wave id over BATCH*SEQ
    const int lane = threadIdx.x & 63;
    const int b    = gw >> 11;          // SEQ = 2048
    const int t    = gw & (SEQ - 1);

    const float4 h4 = ((const float4*)(h_out + ((size_t)b * SEQ + t) * HID))[lane];
    const float4 w4 = ((const float4*)W)[lane];

    float p = h4.x * w4.x + h4.y * w4.y + h4.z * w4.z + h4.w * w4.w;
    #pragma unroll
    for (int s = 32; s; s >>= 1) p += __shfl_xor(p, s, 64);

    if (lane == 0)
        y_out[(size_t)b * SEQ + t] = 1.f / (1.f + __expf(-(p + bvec[0])));
}

extern "C" void kernel_launch(void* const* d_in, const int* in_sizes, int n_in,
                              void* d_out, int out_size, void* d_ws, size_t ws_size,
                              hipStream_t stream) {
    const float* x     = (const float*)d_in[0];
    const float* h0    = (const float*)d_in[1];
    const float* noise = (const float*)d_in[2];
    const float* W_ih  = (const float*)d_in[3];
    const float* W_hh  = (const float*)d_in[4];
    const float* W_hhb = (const float*)d_in[5];
    const float* b_h   = (const float*)d_in[6];
    const float* W     = (const float*)d_in[7];
    const float* bvec  = (const float*)d_in[8];
    const int*   ctx   = (const int*)d_in[9];

    float* y_out = (float*)d_out;                         // (BATCH, SEQ)
    float* h_out = (float*)d_out + (size_t)BATCH * SEQ;   // (BATCH, SEQ, HID)

    rnn_kernel<<<dim3(BATCH), dim3(512), 0, stream>>>(
        x, h0, noise, W_ih, W_hh, W_hhb, b_h, ctx, h_out);

    yproj_kernel<<<dim3(BATCH * SEQ / 4), dim3(256), 0, stream>>>(
        h_out, W, bvec, y_out);
}